// Round 1
// baseline (625.244 us; speedup 1.0000x reference)
//
#include <hip/hip_runtime.h>
#include <math.h>

#define D 512
#define K3D 1536
#define NEGF (-3.40282346638528859812e+38f)

__device__ __forceinline__ int lower_bound_dev(const int* __restrict__ b, int n, int v) {
    int lo = 0, hi = n;
    while (lo < hi) {
        int mid = (lo + hi) >> 1;
        if (b[mid] < v) lo = mid + 1; else hi = mid;
    }
    return lo;
}

__device__ __forceinline__ void acc4(float4& s, float4& q, float4& m, const float4 v) {
    s.x += v.x; s.y += v.y; s.z += v.z; s.w += v.w;
    q.x = fmaf(v.x, v.x, q.x); q.y = fmaf(v.y, v.y, q.y);
    q.z = fmaf(v.z, v.z, q.z); q.w = fmaf(v.w, v.w, q.w);
    m.x = fmaxf(m.x, v.x); m.y = fmaxf(m.y, v.y);
    m.z = fmaxf(m.z, v.z); m.w = fmaxf(m.w, v.w);
}

// One block per segment. 128 threads, 4 consecutive cols each (float4).
__global__ __launch_bounds__(128) void pool_kernel(
    const float* __restrict__ x, const int* __restrict__ batch,
    float* __restrict__ pooled, int n) {
    const int s = blockIdx.x;
    const int tid = threadIdx.x;
    const int start = lower_bound_dev(batch, n, s);
    const int end   = lower_bound_dev(batch, n, s + 1);

    const float4* __restrict__ xv = (const float4*)x;  // row stride = 128 float4

    float4 sum = {0.f, 0.f, 0.f, 0.f};
    float4 sq  = {0.f, 0.f, 0.f, 0.f};
    float4 mx  = {-INFINITY, -INFINITY, -INFINITY, -INFINITY};

    int i = start;
    for (; i + 4 <= end; i += 4) {
        float4 v0 = xv[(size_t)(i + 0) * 128 + tid];
        float4 v1 = xv[(size_t)(i + 1) * 128 + tid];
        float4 v2 = xv[(size_t)(i + 2) * 128 + tid];
        float4 v3 = xv[(size_t)(i + 3) * 128 + tid];
        acc4(sum, sq, mx, v0);
        acc4(sum, sq, mx, v1);
        acc4(sum, sq, mx, v2);
        acc4(sum, sq, mx, v3);
    }
    for (; i < end; ++i) {
        float4 v0 = xv[(size_t)i * 128 + tid];
        acc4(sum, sq, mx, v0);
    }

    const float cnt  = (float)(end - start);
    const float inv  = 1.f / fmaxf(cnt, 1.f);
    const float dinv = 1.f / fmaxf(cnt - 1.f, 1.f);

    float4 mean, stdv, mxo;
    mean.x = sum.x * inv; mean.y = sum.y * inv; mean.z = sum.z * inv; mean.w = sum.w * inv;

    float vx = (sq.x - mean.x * sum.x) * dinv;
    float vy = (sq.y - mean.y * sum.y) * dinv;
    float vz = (sq.z - mean.z * sum.z) * dinv;
    float vw = (sq.w - mean.w * sum.w) * dinv;
    vx = fmaxf(vx, 0.f); vy = fmaxf(vy, 0.f); vz = fmaxf(vz, 0.f); vw = fmaxf(vw, 0.f);
    stdv.x = vx > 0.f ? sqrtf(vx) : 0.f;
    stdv.y = vy > 0.f ? sqrtf(vy) : 0.f;
    stdv.z = vz > 0.f ? sqrtf(vz) : 0.f;
    stdv.w = vw > 0.f ? sqrtf(vw) : 0.f;

    mxo.x = isfinite(mx.x) ? mx.x : NEGF;
    mxo.y = isfinite(mx.y) ? mx.y : NEGF;
    mxo.z = isfinite(mx.z) ? mx.z : NEGF;
    mxo.w = isfinite(mx.w) ? mx.w : NEGF;

    float4* prow = (float4*)(pooled + (size_t)s * K3D);
    prow[tid]       = mean;
    prow[128 + tid] = mxo;
    prow[256 + tid] = stdv;
}

// fp32 GEMM: H[M,512] = pooled[M,1536] @ W[1536,512] + bias
// BM=32 BN=64 BK=32, 128 threads, 4x4 per-thread register tile.
#define BM 32
#define BN 64
#define BK 32
#define LDA 36  // padded leading dim for transposed A tile (keeps 16B align, breaks conflicts)

__global__ __launch_bounds__(128) void gemm_kernel(
    const float* __restrict__ A, const float* __restrict__ W,
    const float* __restrict__ bias, float* __restrict__ H) {
    __shared__ __align__(16) float AsT[BK * LDA];  // [k][m]
    __shared__ __align__(16) float Bs[BK * BN];    // [k][j]

    const int tid = threadIdx.x;
    const int m0 = blockIdx.y * BM;
    const int j0 = blockIdx.x * BN;
    const int tr = tid >> 4;   // 0..7 -> rows 4*tr..4*tr+3
    const int tc = tid & 15;   // 0..15 -> cols 4*tc..4*tc+3

    // loader indices
    const int kq = tid & 7;    // A k-quad: k = 4*kq
    const int am = tid >> 3;   // A m: 0..15 (and +16)
    const int jq = tid & 15;   // B j-quad
    const int kr = tid >> 4;   // B k row: 0..7 (and +8,+16,+24)

    float acc[4][4] = {};

    for (int k0 = 0; k0 < K3D; k0 += BK) {
        float4 a0 = *(const float4*)&A[(size_t)(m0 + am)      * K3D + k0 + 4 * kq];
        float4 a1 = *(const float4*)&A[(size_t)(m0 + am + 16) * K3D + k0 + 4 * kq];
        float4 b0 = *(const float4*)&W[(size_t)(k0 + kr)      * D + j0 + 4 * jq];
        float4 b1 = *(const float4*)&W[(size_t)(k0 + kr +  8) * D + j0 + 4 * jq];
        float4 b2 = *(const float4*)&W[(size_t)(k0 + kr + 16) * D + j0 + 4 * jq];
        float4 b3 = *(const float4*)&W[(size_t)(k0 + kr + 24) * D + j0 + 4 * jq];

        __syncthreads();  // previous tile's LDS reads done
        AsT[(4 * kq + 0) * LDA + am] = a0.x;
        AsT[(4 * kq + 1) * LDA + am] = a0.y;
        AsT[(4 * kq + 2) * LDA + am] = a0.z;
        AsT[(4 * kq + 3) * LDA + am] = a0.w;
        AsT[(4 * kq + 0) * LDA + am + 16] = a1.x;
        AsT[(4 * kq + 1) * LDA + am + 16] = a1.y;
        AsT[(4 * kq + 2) * LDA + am + 16] = a1.z;
        AsT[(4 * kq + 3) * LDA + am + 16] = a1.w;
        *(float4*)&Bs[(kr)      * BN + 4 * jq] = b0;
        *(float4*)&Bs[(kr +  8) * BN + 4 * jq] = b1;
        *(float4*)&Bs[(kr + 16) * BN + 4 * jq] = b2;
        *(float4*)&Bs[(kr + 24) * BN + 4 * jq] = b3;
        __syncthreads();

#pragma unroll
        for (int kk = 0; kk < BK; ++kk) {
            float4 av = *(const float4*)&AsT[kk * LDA + 4 * tr];
            float4 bv = *(const float4*)&Bs[kk * BN + 4 * tc];
            acc[0][0] = fmaf(av.x, bv.x, acc[0][0]);
            acc[0][1] = fmaf(av.x, bv.y, acc[0][1]);
            acc[0][2] = fmaf(av.x, bv.z, acc[0][2]);
            acc[0][3] = fmaf(av.x, bv.w, acc[0][3]);
            acc[1][0] = fmaf(av.y, bv.x, acc[1][0]);
            acc[1][1] = fmaf(av.y, bv.y, acc[1][1]);
            acc[1][2] = fmaf(av.y, bv.z, acc[1][2]);
            acc[1][3] = fmaf(av.y, bv.w, acc[1][3]);
            acc[2][0] = fmaf(av.z, bv.x, acc[2][0]);
            acc[2][1] = fmaf(av.z, bv.y, acc[2][1]);
            acc[2][2] = fmaf(av.z, bv.z, acc[2][2]);
            acc[2][3] = fmaf(av.z, bv.w, acc[2][3]);
            acc[3][0] = fmaf(av.w, bv.x, acc[3][0]);
            acc[3][1] = fmaf(av.w, bv.y, acc[3][1]);
            acc[3][2] = fmaf(av.w, bv.z, acc[3][2]);
            acc[3][3] = fmaf(av.w, bv.w, acc[3][3]);
        }
    }

    const float4 bb = *(const float4*)&bias[j0 + 4 * tc];
#pragma unroll
    for (int i = 0; i < 4; ++i) {
        float4 o;
        o.x = acc[i][0] + bb.x;
        o.y = acc[i][1] + bb.y;
        o.z = acc[i][2] + bb.z;
        o.w = acc[i][3] + bb.w;
        *(float4*)&H[(size_t)(m0 + 4 * tr + i) * D + j0 + 4 * tc] = o;
    }
}

// LayerNorm(d=512) + affine + LeakyReLU. One block per row, 128 threads x float4.
__global__ __launch_bounds__(128) void ln_kernel(
    const float* __restrict__ H, const float* __restrict__ gamma,
    const float* __restrict__ beta, float* __restrict__ out) {
    const int row = blockIdx.x;
    const int tid = threadIdx.x;
    float4 v = *(const float4*)&H[(size_t)row * D + 4 * tid];

    float s = v.x + v.y + v.z + v.w;
    float q = v.x * v.x + v.y * v.y + v.z * v.z + v.w * v.w;
#pragma unroll
    for (int off = 32; off > 0; off >>= 1) {
        s += __shfl_down(s, off);
        q += __shfl_down(q, off);
    }
    __shared__ float ls[2], lq[2];
    const int wave = tid >> 6, lane = tid & 63;
    if (lane == 0) { ls[wave] = s; lq[wave] = q; }
    __syncthreads();
    s = ls[0] + ls[1];
    q = lq[0] + lq[1];

    const float mu = s * (1.f / 512.f);
    float var = q * (1.f / 512.f) - mu * mu;
    var = fmaxf(var, 0.f);
    const float r = rsqrtf(var + 1e-5f);

    float4 g  = *(const float4*)&gamma[4 * tid];
    float4 bt = *(const float4*)&beta[4 * tid];
    float4 o;
    o.x = (v.x - mu) * r * g.x + bt.x;
    o.y = (v.y - mu) * r * g.y + bt.y;
    o.z = (v.z - mu) * r * g.z + bt.z;
    o.w = (v.w - mu) * r * g.w + bt.w;
    o.x = o.x >= 0.f ? o.x : 0.01f * o.x;
    o.y = o.y >= 0.f ? o.y : 0.01f * o.y;
    o.z = o.z >= 0.f ? o.z : 0.01f * o.z;
    o.w = o.w >= 0.f ? o.w : 0.01f * o.w;
    *(float4*)&out[(size_t)row * D + 4 * tid] = o;
}

extern "C" void kernel_launch(void* const* d_in, const int* in_sizes, int n_in,
                              void* d_out, int out_size, void* d_ws, size_t ws_size,
                              hipStream_t stream) {
    const float* x     = (const float*)d_in[0];
    const float* W     = (const float*)d_in[1];
    const float* b     = (const float*)d_in[2];
    const float* gamma = (const float*)d_in[3];
    const float* beta  = (const float*)d_in[4];
    const int*   batch = (const int*)d_in[5];
    const int n = in_sizes[5];
    const int S = out_size / D;  // 1024 (host-known; num_segments value is on device)

    float* pooled = (float*)d_ws;                      // [S, 1536]
    float* H      = pooled + (size_t)S * K3D;          // [S, 512]
    float* out    = (float*)d_out;

    pool_kernel<<<S, 128, 0, stream>>>(x, batch, pooled, n);
    dim3 g2(D / BN, S / BM);  // (8, 32)
    gemm_kernel<<<g2, 128, 0, stream>>>(pooled, W, b, H);
    ln_kernel<<<S, 128, 0, stream>>>(H, gamma, beta, out);
}

// Round 2
// 583.139 us; speedup vs baseline: 1.0722x; 1.0722x over previous
//
#include <hip/hip_runtime.h>
#include <math.h>

#define D 512
#define K3D 1536
#define NEGF (-3.40282346638528859812e+38f)

__device__ __forceinline__ int lower_bound_dev(const int* __restrict__ b, int n, int v) {
    int lo = 0, hi = n;
    while (lo < hi) {
        int mid = (lo + hi) >> 1;
        if (b[mid] < v) lo = mid + 1; else hi = mid;
    }
    return lo;
}

__device__ __forceinline__ void acc4(float4& s, float4& q, float4& m, const float4 v) {
    s.x += v.x; s.y += v.y; s.z += v.z; s.w += v.w;
    q.x = fmaf(v.x, v.x, q.x); q.y = fmaf(v.y, v.y, q.y);
    q.z = fmaf(v.z, v.z, q.z); q.w = fmaf(v.w, v.w, q.w);
    m.x = fmaxf(m.x, v.x); m.y = fmaxf(m.y, v.y);
    m.z = fmaxf(m.z, v.z); m.w = fmaxf(m.w, v.w);
}

// One block per segment. 256 threads: col = tid&127 (float4 col), rw = tid>>7
// (row parity). Each parity accumulates every other row; LDS combine at end.
__global__ __launch_bounds__(256) void pool_kernel(
    const float* __restrict__ x, const int* __restrict__ batch,
    float* __restrict__ pooled, int n) {
    const int s   = blockIdx.x;
    const int col = threadIdx.x & 127;
    const int rw  = threadIdx.x >> 7;
    const int start = lower_bound_dev(batch, n, s);
    const int end   = lower_bound_dev(batch, n, s + 1);

    const float4* __restrict__ xv = (const float4*)x;  // row stride = 128 float4

    float4 sum = {0.f, 0.f, 0.f, 0.f};
    float4 sq  = {0.f, 0.f, 0.f, 0.f};
    float4 mx  = {-INFINITY, -INFINITY, -INFINITY, -INFINITY};

    int i = start + rw;
    for (; i + 6 < end; i += 8) {
        float4 v0 = xv[(size_t)(i + 0) * 128 + col];
        float4 v1 = xv[(size_t)(i + 2) * 128 + col];
        float4 v2 = xv[(size_t)(i + 4) * 128 + col];
        float4 v3 = xv[(size_t)(i + 6) * 128 + col];
        acc4(sum, sq, mx, v0);
        acc4(sum, sq, mx, v1);
        acc4(sum, sq, mx, v2);
        acc4(sum, sq, mx, v3);
    }
    for (; i < end; i += 2) {
        float4 v0 = xv[(size_t)i * 128 + col];
        acc4(sum, sq, mx, v0);
    }

    __shared__ __align__(16) float4 red[3 * 128];
    if (rw == 1) {
        red[col]       = sum;
        red[128 + col] = sq;
        red[256 + col] = mx;
    }
    __syncthreads();
    if (rw == 0) {
        float4 s2 = red[col], q2 = red[128 + col], m2 = red[256 + col];
        sum.x += s2.x; sum.y += s2.y; sum.z += s2.z; sum.w += s2.w;
        sq.x  += q2.x; sq.y  += q2.y; sq.z  += q2.z; sq.w  += q2.w;
        mx.x = fmaxf(mx.x, m2.x); mx.y = fmaxf(mx.y, m2.y);
        mx.z = fmaxf(mx.z, m2.z); mx.w = fmaxf(mx.w, m2.w);

        const float cnt  = (float)(end - start);
        const float inv  = 1.f / fmaxf(cnt, 1.f);
        const float dinv = 1.f / fmaxf(cnt - 1.f, 1.f);

        float4 mean, stdv, mxo;
        mean.x = sum.x * inv; mean.y = sum.y * inv;
        mean.z = sum.z * inv; mean.w = sum.w * inv;

        float vx = (sq.x - mean.x * sum.x) * dinv;
        float vy = (sq.y - mean.y * sum.y) * dinv;
        float vz = (sq.z - mean.z * sum.z) * dinv;
        float vw = (sq.w - mean.w * sum.w) * dinv;
        vx = fmaxf(vx, 0.f); vy = fmaxf(vy, 0.f);
        vz = fmaxf(vz, 0.f); vw = fmaxf(vw, 0.f);
        stdv.x = vx > 0.f ? sqrtf(vx) : 0.f;
        stdv.y = vy > 0.f ? sqrtf(vy) : 0.f;
        stdv.z = vz > 0.f ? sqrtf(vz) : 0.f;
        stdv.w = vw > 0.f ? sqrtf(vw) : 0.f;

        mxo.x = isfinite(mx.x) ? mx.x : NEGF;
        mxo.y = isfinite(mx.y) ? mx.y : NEGF;
        mxo.z = isfinite(mx.z) ? mx.z : NEGF;
        mxo.w = isfinite(mx.w) ? mx.w : NEGF;

        float4* prow = (float4*)(pooled + (size_t)s * K3D);
        prow[col]       = mean;
        prow[128 + col] = mxo;
        prow[256 + col] = stdv;
    }
}

// fp32 GEMM with split-K: Hp[z][M,512] = pooled[M, kz-range] @ W[kz-range, 512]
// BM=32 BN=64 BK=32, 128 threads, 4x4 register tile, SPLITK=4 (384 K each).
#define BM 32
#define BN 64
#define BK 32
#define LDA 36
#define SPLITK 4
#define KCHUNK (K3D / SPLITK)

__global__ __launch_bounds__(128) void gemm_kernel(
    const float* __restrict__ A, const float* __restrict__ W,
    float* __restrict__ Hp, int S) {
    __shared__ __align__(16) float AsT[BK * LDA];  // [k][m]
    __shared__ __align__(16) float Bs[BK * BN];    // [k][j]

    const int tid = threadIdx.x;
    const int m0 = blockIdx.y * BM;
    const int j0 = blockIdx.x * BN;
    const int kb = blockIdx.z * KCHUNK;
    const int tr = tid >> 4;
    const int tc = tid & 15;

    const int kq = tid & 7;
    const int am = tid >> 3;
    const int jq = tid & 15;
    const int kr = tid >> 4;

    float acc[4][4] = {};

    for (int k0 = kb; k0 < kb + KCHUNK; k0 += BK) {
        float4 a0 = *(const float4*)&A[(size_t)(m0 + am)      * K3D + k0 + 4 * kq];
        float4 a1 = *(const float4*)&A[(size_t)(m0 + am + 16) * K3D + k0 + 4 * kq];
        float4 b0 = *(const float4*)&W[(size_t)(k0 + kr)      * D + j0 + 4 * jq];
        float4 b1 = *(const float4*)&W[(size_t)(k0 + kr +  8) * D + j0 + 4 * jq];
        float4 b2 = *(const float4*)&W[(size_t)(k0 + kr + 16) * D + j0 + 4 * jq];
        float4 b3 = *(const float4*)&W[(size_t)(k0 + kr + 24) * D + j0 + 4 * jq];

        __syncthreads();
        AsT[(4 * kq + 0) * LDA + am] = a0.x;
        AsT[(4 * kq + 1) * LDA + am] = a0.y;
        AsT[(4 * kq + 2) * LDA + am] = a0.z;
        AsT[(4 * kq + 3) * LDA + am] = a0.w;
        AsT[(4 * kq + 0) * LDA + am + 16] = a1.x;
        AsT[(4 * kq + 1) * LDA + am + 16] = a1.y;
        AsT[(4 * kq + 2) * LDA + am + 16] = a1.z;
        AsT[(4 * kq + 3) * LDA + am + 16] = a1.w;
        *(float4*)&Bs[(kr)      * BN + 4 * jq] = b0;
        *(float4*)&Bs[(kr +  8) * BN + 4 * jq] = b1;
        *(float4*)&Bs[(kr + 16) * BN + 4 * jq] = b2;
        *(float4*)&Bs[(kr + 24) * BN + 4 * jq] = b3;
        __syncthreads();

#pragma unroll
        for (int kk = 0; kk < BK; ++kk) {
            float4 av = *(const float4*)&AsT[kk * LDA + 4 * tr];
            float4 bv = *(const float4*)&Bs[kk * BN + 4 * tc];
            acc[0][0] = fmaf(av.x, bv.x, acc[0][0]);
            acc[0][1] = fmaf(av.x, bv.y, acc[0][1]);
            acc[0][2] = fmaf(av.x, bv.z, acc[0][2]);
            acc[0][3] = fmaf(av.x, bv.w, acc[0][3]);
            acc[1][0] = fmaf(av.y, bv.x, acc[1][0]);
            acc[1][1] = fmaf(av.y, bv.y, acc[1][1]);
            acc[1][2] = fmaf(av.y, bv.z, acc[1][2]);
            acc[1][3] = fmaf(av.y, bv.w, acc[1][3]);
            acc[2][0] = fmaf(av.z, bv.x, acc[2][0]);
            acc[2][1] = fmaf(av.z, bv.y, acc[2][1]);
            acc[2][2] = fmaf(av.z, bv.z, acc[2][2]);
            acc[2][3] = fmaf(av.z, bv.w, acc[2][3]);
            acc[3][0] = fmaf(av.w, bv.x, acc[3][0]);
            acc[3][1] = fmaf(av.w, bv.y, acc[3][1]);
            acc[3][2] = fmaf(av.w, bv.z, acc[3][2]);
            acc[3][3] = fmaf(av.w, bv.w, acc[3][3]);
        }
    }

    float* out = Hp + (size_t)blockIdx.z * S * D;
#pragma unroll
    for (int i = 0; i < 4; ++i) {
        float4 o = {acc[i][0], acc[i][1], acc[i][2], acc[i][3]};
        *(float4*)&out[(size_t)(m0 + 4 * tr + i) * D + j0 + 4 * tc] = o;
    }
}

// Reduce 4 split-K partials + bias, then LayerNorm + affine + LeakyReLU.
// One block per row, 128 threads x float4.
__global__ __launch_bounds__(128) void ln_kernel(
    const float* __restrict__ Hp, const float* __restrict__ bias,
    const float* __restrict__ gamma, const float* __restrict__ beta,
    float* __restrict__ out, int S) {
    const int row = blockIdx.x;
    const int tid = threadIdx.x;
    const size_t idx = (size_t)row * 128 + tid;  // float4 index into [S,D]
    const size_t stride = (size_t)S * 128;       // float4 stride per partial

    const float4* hp = (const float4*)Hp;
    float4 v0 = hp[idx];
    float4 v1 = hp[idx + stride];
    float4 v2 = hp[idx + 2 * stride];
    float4 v3 = hp[idx + 3 * stride];
    float4 bb = *(const float4*)&bias[4 * tid];
    float4 v;
    v.x = v0.x + v1.x + v2.x + v3.x + bb.x;
    v.y = v0.y + v1.y + v2.y + v3.y + bb.y;
    v.z = v0.z + v1.z + v2.z + v3.z + bb.z;
    v.w = v0.w + v1.w + v2.w + v3.w + bb.w;

    float s = v.x + v.y + v.z + v.w;
    float q = v.x * v.x + v.y * v.y + v.z * v.z + v.w * v.w;
#pragma unroll
    for (int off = 32; off > 0; off >>= 1) {
        s += __shfl_down(s, off);
        q += __shfl_down(q, off);
    }
    __shared__ float ls[2], lq[2];
    const int wave = tid >> 6, lane = tid & 63;
    if (lane == 0) { ls[wave] = s; lq[wave] = q; }
    __syncthreads();
    s = ls[0] + ls[1];
    q = lq[0] + lq[1];

    const float mu = s * (1.f / 512.f);
    float var = q * (1.f / 512.f) - mu * mu;
    var = fmaxf(var, 0.f);
    const float r = rsqrtf(var + 1e-5f);

    float4 g  = *(const float4*)&gamma[4 * tid];
    float4 bt = *(const float4*)&beta[4 * tid];
    float4 o;
    o.x = (v.x - mu) * r * g.x + bt.x;
    o.y = (v.y - mu) * r * g.y + bt.y;
    o.z = (v.z - mu) * r * g.z + bt.z;
    o.w = (v.w - mu) * r * g.w + bt.w;
    o.x = o.x >= 0.f ? o.x : 0.01f * o.x;
    o.y = o.y >= 0.f ? o.y : 0.01f * o.y;
    o.z = o.z >= 0.f ? o.z : 0.01f * o.z;
    o.w = o.w >= 0.f ? o.w : 0.01f * o.w;
    *(float4*)&out[(size_t)row * D + 4 * tid] = o;
}

extern "C" void kernel_launch(void* const* d_in, const int* in_sizes, int n_in,
                              void* d_out, int out_size, void* d_ws, size_t ws_size,
                              hipStream_t stream) {
    const float* x     = (const float*)d_in[0];
    const float* W     = (const float*)d_in[1];
    const float* b     = (const float*)d_in[2];
    const float* gamma = (const float*)d_in[3];
    const float* beta  = (const float*)d_in[4];
    const int*   batch = (const int*)d_in[5];
    const int n = in_sizes[5];
    const int S = out_size / D;  // 1024

    float* pooled = (float*)d_ws;                       // [S, 1536]
    float* Hp     = pooled + (size_t)S * K3D;           // [SPLITK, S, 512]
    float* out    = (float*)d_out;

    pool_kernel<<<S, 256, 0, stream>>>(x, batch, pooled, n);
    dim3 g2(D / BN, S / BM, SPLITK);  // (8, 32, 4)
    gemm_kernel<<<g2, 128, 0, stream>>>(pooled, W, Hp, S);
    ln_kernel<<<S, 128, 0, stream>>>(Hp, b, gamma, beta, out, S);
}

// Round 3
// 563.400 us; speedup vs baseline: 1.1098x; 1.0350x over previous
//
#include <hip/hip_runtime.h>
#include <math.h>

#define D 512
#define K3D 1536
#define NEGF (-3.40282346638528859812e+38f)

typedef __bf16 bf16x8 __attribute__((ext_vector_type(8)));
typedef unsigned short ushort8v __attribute__((ext_vector_type(8)));
typedef float f32x4 __attribute__((ext_vector_type(4)));

__device__ __forceinline__ unsigned short f2bf(float f) {
    unsigned int u = __float_as_uint(f);
    unsigned int r = (u + 0x7FFFu + ((u >> 16) & 1u)) >> 16;
    return (unsigned short)r;
}

__device__ __forceinline__ int lower_bound_dev(const int* __restrict__ b, int n, int v) {
    int lo = 0, hi = n;
    while (lo < hi) {
        int mid = (lo + hi) >> 1;
        if (b[mid] < v) lo = mid + 1; else hi = mid;
    }
    return lo;
}

__device__ __forceinline__ void acc4(float4& s, float4& q, float4& m, const float4 v) {
    s.x += v.x; s.y += v.y; s.z += v.z; s.w += v.w;
    q.x = fmaf(v.x, v.x, q.x); q.y = fmaf(v.y, v.y, q.y);
    q.z = fmaf(v.z, v.z, q.z); q.w = fmaf(v.w, v.w, q.w);
    m.x = fmaxf(m.x, v.x); m.y = fmaxf(m.y, v.y);
    m.z = fmaxf(m.z, v.z); m.w = fmaxf(m.w, v.w);
}

// One block per segment. 256 threads: col = tid&127 (float4 col), rw = tid>>7
// (row parity). Epilogue writes pooled row in bf16 for the MFMA GEMM.
__global__ __launch_bounds__(256) void pool_kernel(
    const float* __restrict__ x, const int* __restrict__ batch,
    unsigned short* __restrict__ pooled_b, int n) {
    const int s   = blockIdx.x;
    const int col = threadIdx.x & 127;
    const int rw  = threadIdx.x >> 7;
    const int start = lower_bound_dev(batch, n, s);
    const int end   = lower_bound_dev(batch, n, s + 1);

    const float4* __restrict__ xv = (const float4*)x;  // row stride = 128 float4

    float4 sum = {0.f, 0.f, 0.f, 0.f};
    float4 sq  = {0.f, 0.f, 0.f, 0.f};
    float4 mx  = {-INFINITY, -INFINITY, -INFINITY, -INFINITY};

    int i = start + rw;
    for (; i + 6 < end; i += 8) {
        float4 v0 = xv[(size_t)(i + 0) * 128 + col];
        float4 v1 = xv[(size_t)(i + 2) * 128 + col];
        float4 v2 = xv[(size_t)(i + 4) * 128 + col];
        float4 v3 = xv[(size_t)(i + 6) * 128 + col];
        acc4(sum, sq, mx, v0);
        acc4(sum, sq, mx, v1);
        acc4(sum, sq, mx, v2);
        acc4(sum, sq, mx, v3);
    }
    for (; i < end; i += 2) {
        float4 v0 = xv[(size_t)i * 128 + col];
        acc4(sum, sq, mx, v0);
    }

    __shared__ __align__(16) float4 red[3 * 128];
    if (rw == 1) {
        red[col]       = sum;
        red[128 + col] = sq;
        red[256 + col] = mx;
    }
    __syncthreads();
    if (rw == 0) {
        float4 s2 = red[col], q2 = red[128 + col], m2 = red[256 + col];
        sum.x += s2.x; sum.y += s2.y; sum.z += s2.z; sum.w += s2.w;
        sq.x  += q2.x; sq.y  += q2.y; sq.z  += q2.z; sq.w  += q2.w;
        mx.x = fmaxf(mx.x, m2.x); mx.y = fmaxf(mx.y, m2.y);
        mx.z = fmaxf(mx.z, m2.z); mx.w = fmaxf(mx.w, m2.w);

        const float cnt  = (float)(end - start);
        const float inv  = 1.f / fmaxf(cnt, 1.f);
        const float dinv = 1.f / fmaxf(cnt - 1.f, 1.f);

        float4 mean, stdv;
        mean.x = sum.x * inv; mean.y = sum.y * inv;
        mean.z = sum.z * inv; mean.w = sum.w * inv;

        float vx = (sq.x - mean.x * sum.x) * dinv;
        float vy = (sq.y - mean.y * sum.y) * dinv;
        float vz = (sq.z - mean.z * sum.z) * dinv;
        float vw = (sq.w - mean.w * sum.w) * dinv;
        vx = fmaxf(vx, 0.f); vy = fmaxf(vy, 0.f);
        vz = fmaxf(vz, 0.f); vw = fmaxf(vw, 0.f);
        stdv.x = vx > 0.f ? sqrtf(vx) : 0.f;
        stdv.y = vy > 0.f ? sqrtf(vy) : 0.f;
        stdv.z = vz > 0.f ? sqrtf(vz) : 0.f;
        stdv.w = vw > 0.f ? sqrtf(vw) : 0.f;

        float mxx = isfinite(mx.x) ? mx.x : NEGF;
        float mxy = isfinite(mx.y) ? mx.y : NEGF;
        float mxz = isfinite(mx.z) ? mx.z : NEGF;
        float mxw = isfinite(mx.w) ? mx.w : NEGF;

        unsigned short* prow = pooled_b + (size_t)s * K3D;
        ushort4 om = { f2bf(mean.x), f2bf(mean.y), f2bf(mean.z), f2bf(mean.w) };
        ushort4 ox = { f2bf(mxx),    f2bf(mxy),    f2bf(mxz),    f2bf(mxw)    };
        ushort4 os = { f2bf(stdv.x), f2bf(stdv.y), f2bf(stdv.z), f2bf(stdv.w) };
        *(ushort4*)&prow[4 * col]        = om;
        *(ushort4*)&prow[512 + 4 * col]  = ox;
        *(ushort4*)&prow[1024 + 4 * col] = os;
    }
}

// Transpose-convert W [1536,512] fp32 -> Wt [512,1536] bf16 (row n holds W[:,n]).
__global__ __launch_bounds__(256) void wconv_kernel(
    const float* __restrict__ W, unsigned short* __restrict__ Wt) {
    __shared__ float tile[32][33];
    const int c0 = blockIdx.x * 32;  // over N=512
    const int r0 = blockIdx.y * 32;  // over K=1536
    const int t = threadIdx.x;
    const int r = t >> 3, c4 = (t & 7) * 4;
    float4 v = *(const float4*)&W[(size_t)(r0 + r) * D + c0 + c4];
    tile[r][c4 + 0] = v.x; tile[r][c4 + 1] = v.y;
    tile[r][c4 + 2] = v.z; tile[r][c4 + 3] = v.w;
    __syncthreads();
    const int nn = t >> 3, k4 = (t & 7) * 4;
    ushort4 o = { f2bf(tile[k4 + 0][nn]), f2bf(tile[k4 + 1][nn]),
                  f2bf(tile[k4 + 2][nn]), f2bf(tile[k4 + 3][nn]) };
    *(ushort4*)&Wt[(size_t)(c0 + nn) * K3D + r0 + k4] = o;
}

// bf16 MFMA GEMM with split-K:
// Hp[z][M,512] = pooled_b[M, kz] @ Wt[kz, 512]^T-style (Wt rows are W columns).
// 64x64 tile, BK=64, 256 threads (4 waves, each 32x32 = 2x2 of 16x16x32 MFMA).
#define GBM 64
#define GBN 64
#define GBK 64
#define LDT 88     // bf16 elements; row stride 176 B -> bank starts 12r%32, <=2-way
#define GSPLIT 4
#define GKC (K3D / GSPLIT)  // 384

__global__ __launch_bounds__(256) void mfma_gemm(
    const unsigned short* __restrict__ A,   // pooled bf16 [M, 1536]
    const unsigned short* __restrict__ B,   // Wt bf16 [512, 1536]
    float* __restrict__ Hp, int S) {
    __shared__ unsigned short As[GBM * LDT];
    __shared__ unsigned short Bs[GBN * LDT];

    const int tid  = threadIdx.x;
    const int wave = tid >> 6;
    const int lane = tid & 63;
    const int m0 = blockIdx.y * GBM;
    const int n0 = blockIdx.x * GBN;
    const int kb = blockIdx.z * GKC;
    const int wm = (wave & 1) * 32;
    const int wn = (wave >> 1) * 32;

    const int sr = tid >> 3;         // staging row 0..31 (and +32)
    const int sc = (tid & 7) * 8;    // staging col (bf16), 16 B chunks

    const int frow = lane & 15;          // m (or n) within 16-tile
    const int fk   = (lane >> 4) * 8;    // k offset within 32

    f32x4 acc00 = {0.f, 0.f, 0.f, 0.f};
    f32x4 acc01 = {0.f, 0.f, 0.f, 0.f};
    f32x4 acc10 = {0.f, 0.f, 0.f, 0.f};
    f32x4 acc11 = {0.f, 0.f, 0.f, 0.f};

    for (int k0 = kb; k0 < kb + GKC; k0 += GBK) {
        ushort8v a0 = *(const ushort8v*)&A[(size_t)(m0 + sr)      * K3D + k0 + sc];
        ushort8v a1 = *(const ushort8v*)&A[(size_t)(m0 + sr + 32) * K3D + k0 + sc];
        ushort8v b0 = *(const ushort8v*)&B[(size_t)(n0 + sr)      * K3D + k0 + sc];
        ushort8v b1 = *(const ushort8v*)&B[(size_t)(n0 + sr + 32) * K3D + k0 + sc];
        __syncthreads();
        *(ushort8v*)&As[(sr)      * LDT + sc] = a0;
        *(ushort8v*)&As[(sr + 32) * LDT + sc] = a1;
        *(ushort8v*)&Bs[(sr)      * LDT + sc] = b0;
        *(ushort8v*)&Bs[(sr + 32) * LDT + sc] = b1;
        __syncthreads();

#pragma unroll
        for (int ks = 0; ks < GBK; ks += 32) {
            bf16x8 af0 = *(const bf16x8*)&As[(wm + frow)      * LDT + ks + fk];
            bf16x8 af1 = *(const bf16x8*)&As[(wm + 16 + frow) * LDT + ks + fk];
            bf16x8 bv0 = *(const bf16x8*)&Bs[(wn + frow)      * LDT + ks + fk];
            bf16x8 bv1 = *(const bf16x8*)&Bs[(wn + 16 + frow) * LDT + ks + fk];
            acc00 = __builtin_amdgcn_mfma_f32_16x16x32_bf16(af0, bv0, acc00, 0, 0, 0);
            acc01 = __builtin_amdgcn_mfma_f32_16x16x32_bf16(af0, bv1, acc01, 0, 0, 0);
            acc10 = __builtin_amdgcn_mfma_f32_16x16x32_bf16(af1, bv0, acc10, 0, 0, 0);
            acc11 = __builtin_amdgcn_mfma_f32_16x16x32_bf16(af1, bv1, acc11, 0, 0, 0);
        }
    }

    float* out = Hp + (size_t)blockIdx.z * S * D;
    const int orow = (lane >> 4) * 4;   // + reg index
    const int ocol = lane & 15;
#pragma unroll
    for (int r = 0; r < 4; ++r) {
        out[(size_t)(m0 + wm +      orow + r) * D + n0 + wn +      ocol] = acc00[r];
        out[(size_t)(m0 + wm +      orow + r) * D + n0 + wn + 16 + ocol] = acc01[r];
        out[(size_t)(m0 + wm + 16 + orow + r) * D + n0 + wn +      ocol] = acc10[r];
        out[(size_t)(m0 + wm + 16 + orow + r) * D + n0 + wn + 16 + ocol] = acc11[r];
    }
}

// Reduce GSPLIT split-K partials + bias, then LayerNorm + affine + LeakyReLU.
__global__ __launch_bounds__(128) void ln_kernel(
    const float* __restrict__ Hp, const float* __restrict__ bias,
    const float* __restrict__ gamma, const float* __restrict__ beta,
    float* __restrict__ out, int S) {
    const int row = blockIdx.x;
    const int tid = threadIdx.x;
    const size_t idx = (size_t)row * 128 + tid;  // float4 index into [S,D]
    const size_t stride = (size_t)S * 128;       // float4 stride per partial

    const float4* hp = (const float4*)Hp;
    float4 v0 = hp[idx];
    float4 v1 = hp[idx + stride];
    float4 v2 = hp[idx + 2 * stride];
    float4 v3 = hp[idx + 3 * stride];
    float4 bb = *(const float4*)&bias[4 * tid];
    float4 v;
    v.x = (v0.x + v1.x) + (v2.x + v3.x) + bb.x;
    v.y = (v0.y + v1.y) + (v2.y + v3.y) + bb.y;
    v.z = (v0.z + v1.z) + (v2.z + v3.z) + bb.z;
    v.w = (v0.w + v1.w) + (v2.w + v3.w) + bb.w;

    float s = v.x + v.y + v.z + v.w;
    float q = v.x * v.x + v.y * v.y + v.z * v.z + v.w * v.w;
#pragma unroll
    for (int off = 32; off > 0; off >>= 1) {
        s += __shfl_down(s, off);
        q += __shfl_down(q, off);
    }
    __shared__ float ls[2], lq[2];
    const int wave = tid >> 6, lane = tid & 63;
    if (lane == 0) { ls[wave] = s; lq[wave] = q; }
    __syncthreads();
    s = ls[0] + ls[1];
    q = lq[0] + lq[1];

    const float mu = s * (1.f / 512.f);
    float var = q * (1.f / 512.f) - mu * mu;
    var = fmaxf(var, 0.f);
    const float r = rsqrtf(var + 1e-5f);

    float4 g  = *(const float4*)&gamma[4 * tid];
    float4 bt = *(const float4*)&beta[4 * tid];
    float4 o;
    o.x = (v.x - mu) * r * g.x + bt.x;
    o.y = (v.y - mu) * r * g.y + bt.y;
    o.z = (v.z - mu) * r * g.z + bt.z;
    o.w = (v.w - mu) * r * g.w + bt.w;
    o.x = o.x >= 0.f ? o.x : 0.01f * o.x;
    o.y = o.y >= 0.f ? o.y : 0.01f * o.y;
    o.z = o.z >= 0.f ? o.z : 0.01f * o.z;
    o.w = o.w >= 0.f ? o.w : 0.01f * o.w;
    *(float4*)&out[(size_t)row * D + 4 * tid] = o;
}

extern "C" void kernel_launch(void* const* d_in, const int* in_sizes, int n_in,
                              void* d_out, int out_size, void* d_ws, size_t ws_size,
                              hipStream_t stream) {
    const float* x     = (const float*)d_in[0];
    const float* W     = (const float*)d_in[1];
    const float* b     = (const float*)d_in[2];
    const float* gamma = (const float*)d_in[3];
    const float* beta  = (const float*)d_in[4];
    const int*   batch = (const int*)d_in[5];
    const int n = in_sizes[5];
    const int S = out_size / D;  // 1024

    char* ws = (char*)d_ws;
    unsigned short* pooled_b = (unsigned short*)ws;                       // [S,1536] bf16, 3 MB
    unsigned short* Wt       = (unsigned short*)(ws + (size_t)S * K3D * 2);          // [512,1536] bf16
    float*          Hp       = (float*)(ws + (size_t)S * K3D * 2 + (size_t)D * K3D * 2);  // [GSPLIT,S,512] f32
    float* out = (float*)d_out;

    pool_kernel<<<S, 256, 0, stream>>>(x, batch, pooled_b, n);
    dim3 gw(D / 32, K3D / 32);  // (16, 48)
    wconv_kernel<<<gw, 256, 0, stream>>>(W, Wt);
    dim3 gg(D / GBN, S / GBM, GSPLIT);  // (8, 16, 4)
    mfma_gemm<<<gg, 256, 0, stream>>>(pooled_b, Wt, Hp, S);
    ln_kernel<<<S, 128, 0, stream>>>(Hp, b, gamma, beta, out, S);
}